// Round 1
// baseline (524.081 us; speedup 1.0000x reference)
//
#include <hip/hip_runtime.h>
#include <stdint.h>

// Residual VQ, MI355X. N=16384 rows, D=256, K=4096 codes, Q=4 stages.
// Forward value: residual never changes => all stages quantize zn=l2norm(x).
// Distance argmin via fp16 hi/lo split (3 MFMAs ~ fp32-accurate) + exact fp32
// rescue for near-ties (approx gap < MARGIN).

#define NR 16384
#define DIM 256
#define KCB 4096
#define QST 4
#define MARGIN 2e-5f

typedef _Float16 f16;
typedef __attribute__((ext_vector_type(4))) f16 f16x4;
typedef __attribute__((ext_vector_type(8))) f16 f16x8;
typedef __attribute__((ext_vector_type(4))) float f32x4;

// ---- workspace byte offsets (total ~36.3 MB) ----
#define WS_ZN_HI   ((size_t)0)                       // NR*DIM f16 = 8 MB
#define WS_ZN_LO   ((size_t)8*1024*1024)
#define WS_CB_HI   ((size_t)16*1024*1024)            // Q*K*DIM f16 = 8 MB
#define WS_CB_LO   ((size_t)24*1024*1024)
#define WS_NORMS   ((size_t)32*1024*1024)            // NR f32
#define WS_SSQ     (WS_NORMS + 65536)                // Q*K f32
#define WS_TOPS    (WS_SSQ + 65536)                  // Q*NR*2 float4 = 2 MB
#define WS_IDX     (WS_TOPS + (size_t)QST*NR*2*16)   // NR*Q int
#define WS_LIST    (WS_IDX + (size_t)QST*NR*4)       // rescue list
#define WS_CNT     (WS_LIST + (size_t)65536*4)
#define WS_PART    (WS_CNT + 16)                     // 4096 f32 loss partials

__device__ __forceinline__ void gll16(const void* g, void* l) {
  __builtin_amdgcn_global_load_lds(
      (const __attribute__((address_space(1))) void*)g,
      (__attribute__((address_space(3))) void*)l, 16, 0, 0);
}

// ---- prep: per-row sumsq (+optional l2norm), fp16 hi/lo split ----
__global__ void prep_kernel(const float* __restrict__ src, char* __restrict__ ws,
                            int normalize) {
  const int w = threadIdx.x >> 6, lane = threadIdx.x & 63;
  const int row = blockIdx.x * 4 + w;
  const float4 v = ((const float4*)src)[row * 64 + lane];
  float ss = v.x * v.x + v.y * v.y + v.z * v.z + v.w * v.w;
#pragma unroll
  for (int m = 32; m; m >>= 1) ss += __shfl_xor(ss, m);
  float4 z = v;
  f16* hi; f16* lo;
  if (normalize) {
    const float denom = fmaxf(sqrtf(ss), 1e-12f);
    z.x = v.x / denom; z.y = v.y / denom; z.z = v.z / denom; z.w = v.w / denom;
    hi = (f16*)(ws + WS_ZN_HI); lo = (f16*)(ws + WS_ZN_LO);
    if (lane == 0) ((float*)(ws + WS_NORMS))[row] = denom;
    if (blockIdx.x == 0 && threadIdx.x == 0) *(int*)(ws + WS_CNT) = 0;
  } else {
    hi = (f16*)(ws + WS_CB_HI); lo = (f16*)(ws + WS_CB_LO);
    if (lane == 0) ((float*)(ws + WS_SSQ))[row] = ss;
  }
  f16x4 h, l;
  h[0] = (f16)z.x; h[1] = (f16)z.y; h[2] = (f16)z.z; h[3] = (f16)z.w;
  l[0] = (f16)(z.x - (float)h[0]); l[1] = (f16)(z.y - (float)h[1]);
  l[2] = (f16)(z.z - (float)h[2]); l[3] = (f16)(z.w - (float)h[3]);
  ((f16x4*)hi)[row * 64 + lane] = h;
  ((f16x4*)lo)[row * 64 + lane] = l;
}

// ---- score: fused GEMM (hi/lo fp16 x3 MFMA) + per-row top2 over K ----
__launch_bounds__(256, 2)
__global__ void score_kernel(char* __restrict__ ws) {
  // LDS regions: [0]=A_hi [1]=A_lo [2]=B_hi [3]=B_lo, each [128 rows][64 halfs]
  __shared__ __align__(16) f16 smem[4][128][64];  // 64 KB
  const int tid = threadIdx.x, w = tid >> 6, lane = tid & 63;
  const int wr = w >> 1, wc = w & 1;
  const int blk = blockIdx.x;
  const int xcd = blk & 7, st = xcd >> 1;
  const int rowtile = ((xcd & 1) << 6) + (blk >> 3);   // 0..127
  const int rowBase = rowtile << 7;

  const f16* zn_hi = (const f16*)(ws + WS_ZN_HI);
  const f16* zn_lo = (const f16*)(ws + WS_ZN_LO);
  const f16* cb_hi = (const f16*)(ws + WS_CB_HI);
  const f16* cb_lo = (const f16*)(ws + WS_CB_LO);
  const f16* src = (w == 0) ? zn_hi : (w == 1) ? zn_lo : (w == 2) ? cb_hi : cb_lo;
  const int isB = (w >= 2);

  // pre-swizzled global source so linear global_load_lds lands the XOR layout:
  // LDS[row][slot] holds global granule (slot ^ (row&7)); granule = 16B = 8 halfs
  const int g0 = (lane & 7) ^ ((lane >> 3) & 7);
  const size_t laneOff = (size_t)(lane >> 3) * DIM + (size_t)g0 * 8;
  f16* ldsW = &smem[w][0][0];

  const float* ssqp = (const float*)(ws + WS_SSQ) + (size_t)st * KCB;

  float t1[16], t2[16]; int i1[16];
#pragma unroll
  for (int s = 0; s < 16; ++s) { t1[s] = -3.4e38f; t2[s] = -3.4e38f; i1[s] = 0; }

  for (int ct = 0; ct < 32; ++ct) {
    f32x4 acc[4][4];
#pragma unroll
    for (int m = 0; m < 4; ++m)
#pragma unroll
      for (int n = 0; n < 4; ++n) { acc[m][n][0] = 0.f; acc[m][n][1] = 0.f; acc[m][n][2] = 0.f; acc[m][n][3] = 0.f; }

    const int rowG0 = isB ? (st * KCB + ct * 128) : rowBase;
    const f16* srcBase = src + (size_t)rowG0 * DIM + laneOff;

    for (int dc = 0; dc < 4; ++dc) {
      __syncthreads();  // protect LDS reuse from previous iteration's reads
      const f16* sp = srcBase + dc * 64;
#pragma unroll
      for (int op = 0; op < 16; ++op)
        gll16(sp + op * 2048, ldsW + op * 512);
      __syncthreads();  // drains vmcnt before barrier (compiler-emitted)

#pragma unroll
      for (int kk = 0; kk < 2; ++kk) {
        f16x8 ah[4], al[4];
#pragma unroll
        for (int m = 0; m < 4; ++m) {
          const int rl = wr * 64 + m * 16 + (lane & 15);
          const int slot = ((kk << 2) + (lane >> 4)) ^ (rl & 7);
          const int off = rl * 64 + slot * 8;
          ah[m] = *(const f16x8*)(&smem[0][0][0] + off);
          al[m] = *(const f16x8*)(&smem[1][0][0] + off);
        }
#pragma unroll
        for (int n = 0; n < 4; ++n) {
          const int cl = wc * 64 + n * 16 + (lane & 15);
          const int slot = ((kk << 2) + (lane >> 4)) ^ (cl & 7);
          const int off = cl * 64 + slot * 8;
          const f16x8 bh = *(const f16x8*)(&smem[2][0][0] + off);
          const f16x8 bl = *(const f16x8*)(&smem[3][0][0] + off);
#pragma unroll
          for (int m = 0; m < 4; ++m) {
            acc[m][n] = __builtin_amdgcn_mfma_f32_16x16x32_f16(ah[m], bh, acc[m][n], 0, 0, 0);
            acc[m][n] = __builtin_amdgcn_mfma_f32_16x16x32_f16(ah[m], bl, acc[m][n], 0, 0, 0);
            acc[m][n] = __builtin_amdgcn_mfma_f32_16x16x32_f16(al[m], bh, acc[m][n], 0, 0, 0);
          }
        }
      }
    }
    // score = 2*dot - |e|^2 ; argmin dist == argmax score. Track top2 per slot.
#pragma unroll
    for (int n = 0; n < 4; ++n) {
      const int col = ct * 128 + wc * 64 + n * 16 + (lane & 15);
      const float sv = ssqp[col];
#pragma unroll
      for (int m = 0; m < 4; ++m)
#pragma unroll
        for (int r = 0; r < 4; ++r) {
          const float sc = 2.0f * acc[m][n][r] - sv;
          const int sl = m * 4 + r;
          if (sc > t1[sl]) { t2[sl] = t1[sl]; t1[sl] = sc; i1[sl] = col; }
          else t2[sl] = fmaxf(t2[sl], sc);
        }
    }
  }

  // butterfly merge across the 16 lanes holding the same row
  float4* tops = (float4*)(ws + WS_TOPS);
#pragma unroll
  for (int m = 0; m < 4; ++m)
#pragma unroll
    for (int r = 0; r < 4; ++r) {
      const int sl = m * 4 + r;
      float a1 = t1[sl], a2 = t2[sl]; int ai = i1[sl];
#pragma unroll
      for (int msk = 1; msk < 16; msk <<= 1) {
        const float o1 = __shfl_xor(a1, msk);
        const float o2 = __shfl_xor(a2, msk);
        const int   oi = __shfl_xor(ai, msk);
        if (o1 > a1)       { a2 = fmaxf(a1, o2); a1 = o1; ai = oi; }
        else if (o1 == a1) { a2 = a1; ai = min(ai, oi); }
        else               { a2 = fmaxf(a2, o1); }
      }
      if ((lane & 15) == 0) {
        const int row = rowBase + wr * 64 + m * 16 + (lane >> 4) * 4 + r;
        tops[((size_t)st * NR + row) * 2 + wc] =
            make_float4(a1, a2, __int_as_float(ai), 0.f);
      }
    }
}

// ---- merge wave-halves, pick index, flag near-ties for exact rescue ----
__global__ void merge_flag_kernel(char* __restrict__ ws) {
  const int t = blockIdx.x * 256 + threadIdx.x;  // t = row*4 + stage
  const int row = t >> 2, st = t & 3;
  const float4* tops = (const float4*)(ws + WS_TOPS);
  const float4 a = tops[((size_t)st * NR + row) * 2 + 0];
  const float4 b = tops[((size_t)st * NR + row) * 2 + 1];
  float t1, t2; int i1;
  if (a.x > b.x)      { t1 = a.x; t2 = fmaxf(a.y, b.x); i1 = __float_as_int(a.z); }
  else if (b.x > a.x) { t1 = b.x; t2 = fmaxf(b.y, a.x); i1 = __float_as_int(b.z); }
  else { t1 = a.x; t2 = a.x; i1 = min(__float_as_int(a.z), __float_as_int(b.z)); }
  ((int*)(ws + WS_IDX))[t] = i1;
  if (t1 - t2 < MARGIN) {
    const int p = atomicAdd((int*)(ws + WS_CNT), 1);
    if (p < 65536) ((int*)(ws + WS_LIST))[p] = t;
  }
}

// ---- exact fp32 re-scan for flagged (row,stage), numpy-rounding-faithful ----
__global__ void rescue_kernel(const float* __restrict__ x, const float* __restrict__ cb,
                              char* __restrict__ ws) {
  __shared__ float zrow[DIM];
  __shared__ float bv[256];
  __shared__ int bi[256];
  const int tid = threadIdx.x;
  int cnt = *(const int*)(ws + WS_CNT);
  if (cnt > 65536) cnt = 65536;
  for (int i = blockIdx.x; i < cnt; i += gridDim.x) {
    const int t = ((const int*)(ws + WS_LIST))[i];
    const int row = t >> 2, st = t & 3;
    const float denom = ((const float*)(ws + WS_NORMS))[row];
    zrow[tid] = x[(size_t)row * DIM + tid] / denom;
    __syncthreads();
    float zs = zrow[tid] * zrow[tid];
#pragma unroll
    for (int m = 32; m; m >>= 1) zs += __shfl_xor(zs, m);
    if ((tid & 63) == 0) bv[tid >> 6] = zs;
    __syncthreads();
    const float zsq = bv[0] + bv[1] + bv[2] + bv[3];
    __syncthreads();

    const float* cbs = cb + (size_t)st * KCB * DIM;
    const float* ssqp = (const float*)(ws + WS_SSQ) + (size_t)st * KCB;
    float best = 3.4e38f; int bidx = 0x7fffffff;
    for (int k = tid; k < KCB; k += 256) {
      const float4* cr = (const float4*)(cbs + (size_t)k * DIM);
      const float4* zr = (const float4*)zrow;
      float dot = 0.f;
      for (int d = 0; d < 64; ++d) {
        const float4 c = cr[d], z = zr[d];
        dot += c.x * z.x + c.y * z.y + c.z * z.z + c.w * z.w;
      }
      const float aa = zsq + ssqp[k];        // match numpy: (zsq+ssq) - 2*dot
      const float dist = aa - 2.0f * dot;
      if (dist < best) { best = dist; bidx = k; }
    }
    bv[tid] = best; bi[tid] = bidx;
    __syncthreads();
    for (int off = 128; off; off >>= 1) {
      if (tid < off) {
        if (bv[tid + off] < bv[tid] ||
            (bv[tid + off] == bv[tid] && bi[tid + off] < bi[tid])) {
          bv[tid] = bv[tid + off]; bi[tid] = bi[tid + off];
        }
      }
      __syncthreads();
    }
    if (tid == 0) ((int*)(ws + WS_IDX))[t] = bi[0];
    __syncthreads();
  }
}

// ---- gather codewords, quantized sum, loss partials, indices(as float) ----
__global__ void finalize_kernel(const float* __restrict__ x, const float* __restrict__ cb,
                                char* __restrict__ ws, float* __restrict__ out) {
  __shared__ float wsum[4];
  const int w = threadIdx.x >> 6, lane = threadIdx.x & 63;
  const int row = blockIdx.x * 4 + w;
  const int* idxp = (const int*)(ws + WS_IDX) + (size_t)row * 4;
  const float denom = ((const float*)(ws + WS_NORMS))[row];
  const float4 xv = ((const float4*)x)[row * 64 + lane];
  const float4 zn = make_float4(xv.x / denom, xv.y / denom, xv.z / denom, xv.w / denom);
  float4 s = make_float4(0.f, 0.f, 0.f, 0.f);
  float lacc = 0.f;
#pragma unroll
  for (int q = 0; q < 4; ++q) {
    const int id = idxp[q];
    const float4 e = ((const float4*)(cb + ((size_t)q * KCB + id) * DIM))[lane];
    s.x += e.x; s.y += e.y; s.z += e.z; s.w += e.w;
    const float dx = e.x - zn.x, dy = e.y - zn.y, dz = e.z - zn.z, dw = e.w - zn.w;
    lacc += dx * dx + dy * dy + dz * dz + dw * dw;
  }
  ((float4*)out)[row * 64 + lane] = s;
  if (lane < 4) out[4194305 + (size_t)row * 4 + lane] = (float)idxp[lane];
#pragma unroll
  for (int m = 32; m; m >>= 1) lacc += __shfl_xor(lacc, m);
  if (lane == 0) wsum[w] = lacc;
  __syncthreads();
  if (threadIdx.x == 0)
    ((float*)(ws + WS_PART))[blockIdx.x] = wsum[0] + wsum[1] + wsum[2] + wsum[3];
}

__global__ void loss_final_kernel(const char* __restrict__ ws, float* __restrict__ out) {
  __shared__ float wsum[4];
  const int tid = threadIdx.x, w = tid >> 6, lane = tid & 63;
  const float* p = (const float*)(ws + WS_PART);
  float s = 0.f;
  for (int i = tid; i < 4096; i += 256) s += p[i];
#pragma unroll
  for (int m = 32; m; m >>= 1) s += __shfl_xor(s, m);
  if (lane == 0) wsum[w] = s;
  __syncthreads();
  if (tid == 0)
    out[4194304] = (wsum[0] + wsum[1] + wsum[2] + wsum[3]) * (1.0f / 4194304.0f);
}

extern "C" void kernel_launch(void* const* d_in, const int* in_sizes, int n_in,
                              void* d_out, int out_size, void* d_ws, size_t ws_size,
                              hipStream_t stream) {
  (void)in_sizes; (void)n_in; (void)out_size; (void)ws_size;
  const float* x = (const float*)d_in[0];
  const float* cb = (const float*)d_in[1];
  float* out = (float*)d_out;
  char* ws = (char*)d_ws;

  hipLaunchKernelGGL(prep_kernel, dim3(NR / 4), dim3(256), 0, stream, x, ws, 1);
  hipLaunchKernelGGL(prep_kernel, dim3(NR / 4), dim3(256), 0, stream, cb, ws, 0);
  hipLaunchKernelGGL(score_kernel, dim3(512), dim3(256), 0, stream, ws);
  hipLaunchKernelGGL(merge_flag_kernel, dim3((NR * QST) / 256), dim3(256), 0, stream, ws);
  hipLaunchKernelGGL(rescue_kernel, dim3(256), dim3(256), 0, stream, x, cb, ws);
  hipLaunchKernelGGL(finalize_kernel, dim3(NR / 4), dim3(256), 0, stream, x, cb, ws, out);
  hipLaunchKernelGGL(loss_final_kernel, dim3(1), dim3(256), 0, stream, ws, out);
}